// Round 2
// baseline (98.776 us; speedup 1.0000x reference)
//
#include <hip/hip_runtime.h>
#include <math.h>

// BispectrumCalculator:
//   y = fft(target)  [B,T,N] complex
//   Bx[k,l] = y[k] * conj(y[l]) * y[(l-k) mod N]
//   source = stack([Bx.re, Bx.im], ch).mean(T)  -> [B, 2, N, N]
//   outputs: (source, target)  -> d_out = source flat (16,777,216) ++ target flat (65,536)

#define NN 512
#define TT 4
#define BB 32

// ---------------------------------------------------------------------------
// Kernel A: naive DFT-512 per (b,t). 512 blocks x 128 threads; each block
// covers one quarter of the k-range for one (b,t). x[n] reads are
// wave-uniform -> scalar loads. Twiddles via 4 independent complex rotors
// (no LDS table -> no bank conflicts, ILP across the serial rotation chain).
// ---------------------------------------------------------------------------
__global__ __launch_bounds__(128) void dft_kernel(const float* __restrict__ x,
                                                  float2* __restrict__ y) {
    int bt = blockIdx.x >> 2;
    int k  = ((blockIdx.x & 3) << 7) | threadIdx.x;
    const float* xp = x + (size_t)bt * NN;

    float ang = -2.0f * (float)M_PI * (float)k / (float)NN;

    // rotors w[j] = exp(i*ang*j), advanced by exp(i*ang*4) each group of 4
    float2 w0, w1, w2, w3;
    float s4, c4;
    w0 = make_float2(1.0f, 0.0f);
    sincosf(ang,        &w1.y, &w1.x);
    sincosf(2.0f * ang, &w2.y, &w2.x);
    sincosf(3.0f * ang, &w3.y, &w3.x);
    sincosf(4.0f * ang, &s4,   &c4);

    float2 a0 = make_float2(0.f, 0.f), a1 = a0, a2 = a0, a3 = a0;

    #pragma unroll 4
    for (int n = 0; n < NN; n += 4) {
        float x0 = xp[n];
        float x1 = xp[n + 1];
        float x2 = xp[n + 2];
        float x3 = xp[n + 3];
        a0.x += x0 * w0.x; a0.y += x0 * w0.y;
        a1.x += x1 * w1.x; a1.y += x1 * w1.y;
        a2.x += x2 * w2.x; a2.y += x2 * w2.y;
        a3.x += x3 * w3.x; a3.y += x3 * w3.y;
        float t;
        t = w0.x * c4 - w0.y * s4; w0.y = w0.x * s4 + w0.y * c4; w0.x = t;
        t = w1.x * c4 - w1.y * s4; w1.y = w1.x * s4 + w1.y * c4; w1.x = t;
        t = w2.x * c4 - w2.y * s4; w2.y = w2.x * s4 + w2.y * c4; w2.x = t;
        t = w3.x * c4 - w3.y * s4; w3.y = w3.x * s4 + w3.y * c4; w3.x = t;
    }

    float re = (a0.x + a1.x) + (a2.x + a3.x);
    float im = (a0.y + a1.y) + (a2.y + a3.y);
    y[(size_t)bt * NN + k] = make_float2(re, im);
}

// ---------------------------------------------------------------------------
// Kernel B: bispectrum. Grid = B * 64 blocks of 256 threads.
// Each block: one b, 8 consecutive k-rows. y[b] (16 KiB) staged in LDS.
// Thread owns l = tid and l = tid+256:
//   - c-reads lane-contiguous float2 -> conflict-free (2 lanes/bank = free)
//   - idx for second half = idx0 ^ 256  ((x+256)%512 == x^256)
//   - stores: 4 coalesced dword streams (256 contiguous B per wave-store)
// Bx = (y[k] * y[(l-k)]) * conj(y[l])   (regrouped; same value in fp32-land)
// ---------------------------------------------------------------------------
__global__ __launch_bounds__(256) void bispec_kernel(const float2* __restrict__ y,
                                                     float* __restrict__ out) {
    __shared__ float2 ys[TT * NN];  // 16 KiB

    int b     = blockIdx.x >> 6;
    int kbase = (blockIdx.x & 63) << 3;

    // stage y[b] -> LDS (1024 float4 with 256 threads)
    const float4* src = (const float4*)(y + (size_t)b * TT * NN);
    float4* dst = (float4*)ys;
    #pragma unroll
    for (int i = 0; i < 4; ++i)
        dst[threadIdx.x + 256 * i] = src[threadIdx.x + 256 * i];
    __syncthreads();

    int l0 = threadIdx.x;  // second l is l0 + 256

    // preload conj-target values (k-invariant), conflict-free contiguous reads
    float2 b0[TT], b1[TT];
    #pragma unroll
    for (int t = 0; t < TT; ++t) {
        b0[t] = ys[t * NN + l0];
        b1[t] = ys[t * NN + l0 + 256];
    }

    float* outb = out + (size_t)b * 2 * NN * NN;

    #pragma unroll
    for (int kk = 0; kk < 8; ++kk) {
        int k = kbase + kk;
        int idx0 = (l0 - k) & (NN - 1);
        int idx1 = idx0 ^ 256;
        float r0 = 0.f, i0 = 0.f, r1 = 0.f, i1 = 0.f;
        #pragma unroll
        for (int t = 0; t < TT; ++t) {
            float2 a  = ys[t * NN + k];      // wave-uniform broadcast
            float2 c0 = ys[t * NN + idx0];   // contiguous across lanes
            float2 c1 = ys[t * NN + idx1];
            // u = a * c
            float ur0 = a.x * c0.x - a.y * c0.y;
            float ui0 = a.x * c0.y + a.y * c0.x;
            r0 += ur0 * b0[t].x + ui0 * b0[t].y;   // (u * conj(bv)).re
            i0 += ui0 * b0[t].x - ur0 * b0[t].y;   // (u * conj(bv)).im
            float ur1 = a.x * c1.x - a.y * c1.y;
            float ui1 = a.x * c1.y + a.y * c1.x;
            r1 += ur1 * b1[t].x + ui1 * b1[t].y;
            i1 += ui1 * b1[t].x - ur1 * b1[t].y;
        }
        size_t rk = (size_t)k * NN + l0;
        outb[rk]                 = r0 * 0.25f;  // real ch, l0
        outb[rk + 256]           = r1 * 0.25f;  // real ch, l0+256
        outb[NN * NN + rk]       = i0 * 0.25f;  // imag ch, l0
        outb[NN * NN + rk + 256] = i1 * 0.25f;  // imag ch, l0+256
    }
}

extern "C" void kernel_launch(void* const* d_in, const int* in_sizes, int n_in,
                              void* d_out, int out_size, void* d_ws, size_t ws_size,
                              hipStream_t stream) {
    const float* target = (const float*)d_in[0];
    float* out = (float*)d_out;
    // workspace: y spectrum, B*T*N complex64 = 512 KiB
    float2* y = (float2*)d_ws;

    dft_kernel<<<BB * TT * 4, 128, 0, stream>>>(target, y);
    bispec_kernel<<<BB * 64, 256, 0, stream>>>(y, out);

    // second tuple output: target passthrough
    hipMemcpyAsync(out + (size_t)BB * 2 * NN * NN, target,
                   (size_t)BB * TT * NN * sizeof(float),
                   hipMemcpyDeviceToDevice, stream);
}

// Round 3
// 97.426 us; speedup vs baseline: 1.0138x; 1.0138x over previous
//
#include <hip/hip_runtime.h>
#include <math.h>

// BispectrumCalculator:
//   y = fft(target)  [B,T,N] complex
//   Bx[k,l] = y[k] * conj(y[l]) * y[(l-k) mod N]
//   source = stack([Bx.re, Bx.im], ch).mean(T)  -> [B, 2, N, N]
//   outputs: (source, target)  -> d_out = source flat (16,777,216) ++ target flat (65,536)
//
// NOTE (r2 post-mortem): measured window includes harness re-poison of d_ws
// (257 MiB, ~46us) + d_out (64 MiB, ~12us); controllable slice is ~35-40us.

#define NN 512
#define TT 4
#define BB 32

// ---------------------------------------------------------------------------
// Kernel A: naive DFT-512 per (b,t). 512 blocks x 128 threads. Unchanged
// from r1/r2 (isolates the bispec change).
// ---------------------------------------------------------------------------
__global__ __launch_bounds__(128) void dft_kernel(const float* __restrict__ x,
                                                  float2* __restrict__ y) {
    int bt = blockIdx.x >> 2;
    int k  = ((blockIdx.x & 3) << 7) | threadIdx.x;
    const float* xp = x + (size_t)bt * NN;

    float ang = -2.0f * (float)M_PI * (float)k / (float)NN;

    float2 w0, w1, w2, w3;
    float s4, c4;
    w0 = make_float2(1.0f, 0.0f);
    sincosf(ang,        &w1.y, &w1.x);
    sincosf(2.0f * ang, &w2.y, &w2.x);
    sincosf(3.0f * ang, &w3.y, &w3.x);
    sincosf(4.0f * ang, &s4,   &c4);

    float2 a0 = make_float2(0.f, 0.f), a1 = a0, a2 = a0, a3 = a0;

    #pragma unroll 4
    for (int n = 0; n < NN; n += 4) {
        float x0 = xp[n];
        float x1 = xp[n + 1];
        float x2 = xp[n + 2];
        float x3 = xp[n + 3];
        a0.x += x0 * w0.x; a0.y += x0 * w0.y;
        a1.x += x1 * w1.x; a1.y += x1 * w1.y;
        a2.x += x2 * w2.x; a2.y += x2 * w2.y;
        a3.x += x3 * w3.x; a3.y += x3 * w3.y;
        float t;
        t = w0.x * c4 - w0.y * s4; w0.y = w0.x * s4 + w0.y * c4; w0.x = t;
        t = w1.x * c4 - w1.y * s4; w1.y = w1.x * s4 + w1.y * c4; w1.x = t;
        t = w2.x * c4 - w2.y * s4; w2.y = w2.x * s4 + w2.y * c4; w2.x = t;
        t = w3.x * c4 - w3.y * s4; w3.y = w3.x * s4 + w3.y * c4; w3.x = t;
    }

    float re = (a0.x + a1.x) + (a2.x + a3.x);
    float im = (a0.y + a1.y) + (a2.y + a3.y);
    y[(size_t)bt * NN + k] = make_float2(re, im);
}

// ---------------------------------------------------------------------------
// Kernel B: bispectrum, register-sliding-window version.
// Grid = B * 64 blocks of 256 threads; block = one b, 8 consecutive k-rows.
// LDS holds y[b] as a DOUBLED ring per t (ring[i] == ring[i+512]) so any
// 8-element window (l0-k for the block's 8 k's) is contiguous -> the
// compiler pairs the reads into ds_read2_b64. c-window and a-values are
// read ONCE per t and reused across all 8 k -> LDS read insts/thread drop
// ~104 -> ~56. l = tid and tid+256 (lane-contiguous, conflict-free).
// ---------------------------------------------------------------------------
__global__ __launch_bounds__(256) void bispec_kernel(const float2* __restrict__ y,
                                                     float* __restrict__ out) {
    __shared__ float2 ring[TT * 2 * NN];  // 32 KiB, doubled ring per t

    int b     = blockIdx.x >> 6;
    int kbase = (blockIdx.x & 63) << 3;
    int tid   = threadIdx.x;

    // stage y[b] -> doubled LDS ring (global: [t][256] float4)
    const float4* src = (const float4*)(y + (size_t)b * TT * NN);
    float4* dst4 = (float4*)ring;
    #pragma unroll
    for (int i = 0; i < 4; ++i) {
        int g = tid + 256 * i;          // [0,1024)
        int t = g >> 8;
        int j = g & 255;
        float4 v = src[g];
        dst4[(t << 9) + j]       = v;
        dst4[(t << 9) + j + 256] = v;
    }
    __syncthreads();

    int l0 = tid;  // second l is l0 + 256

    // conj-source values, k-invariant
    float2 b0[TT], b1[TT];
    #pragma unroll
    for (int t = 0; t < TT; ++t) {
        b0[t] = ring[(t << 10) + l0];
        b1[t] = ring[(t << 10) + l0 + 256];
    }

    float r0[8], i0[8], r1[8], i1[8];
    #pragma unroll
    for (int kk = 0; kk < 8; ++kk) { r0[kk] = i0[kk] = r1[kk] = i1[kk] = 0.f; }

    int w0base = (l0 - kbase - 7) & (NN - 1);        // window start, half 0
    int w1base = (l0 + 256 - kbase - 7) & (NN - 1);  // window start, half 1

    #pragma unroll
    for (int t = 0; t < TT; ++t) {
        const float2* rt = ring + (t << 10);
        // c windows: 8 consecutive float2 each (ring removes the wrap)
        float2 cw0[8], cw1[8], av[8];
        #pragma unroll
        for (int j = 0; j < 8; ++j) {
            cw0[j] = rt[w0base + j];
            cw1[j] = rt[w1base + j];
            av[j]  = rt[kbase + j];   // wave-uniform broadcast
        }
        #pragma unroll
        for (int kk = 0; kk < 8; ++kk) {
            float2 a  = av[kk];
            float2 c0 = cw0[7 - kk];
            float2 c1 = cw1[7 - kk];
            float ur0 = a.x * c0.x - a.y * c0.y;
            float ui0 = a.x * c0.y + a.y * c0.x;
            r0[kk] += ur0 * b0[t].x + ui0 * b0[t].y;
            i0[kk] += ui0 * b0[t].x - ur0 * b0[t].y;
            float ur1 = a.x * c1.x - a.y * c1.y;
            float ui1 = a.x * c1.y + a.y * c1.x;
            r1[kk] += ur1 * b1[t].x + ui1 * b1[t].y;
            i1[kk] += ui1 * b1[t].x - ur1 * b1[t].y;
        }
    }

    float* outb = out + (size_t)b * 2 * NN * NN;
    #pragma unroll
    for (int kk = 0; kk < 8; ++kk) {
        size_t rk = (size_t)(kbase + kk) * NN + l0;
        outb[rk]                 = r0[kk] * 0.25f;  // real ch, l0
        outb[rk + 256]           = r1[kk] * 0.25f;  // real ch, l0+256
        outb[NN * NN + rk]       = i0[kk] * 0.25f;  // imag ch, l0
        outb[NN * NN + rk + 256] = i1[kk] * 0.25f;  // imag ch, l0+256
    }
}

extern "C" void kernel_launch(void* const* d_in, const int* in_sizes, int n_in,
                              void* d_out, int out_size, void* d_ws, size_t ws_size,
                              hipStream_t stream) {
    const float* target = (const float*)d_in[0];
    float* out = (float*)d_out;
    // workspace: y spectrum, B*T*N complex64 = 512 KiB
    float2* y = (float2*)d_ws;

    dft_kernel<<<BB * TT * 4, 128, 0, stream>>>(target, y);
    bispec_kernel<<<BB * 64, 256, 0, stream>>>(y, out);

    // second tuple output: target passthrough
    hipMemcpyAsync(out + (size_t)BB * 2 * NN * NN, target,
                   (size_t)BB * TT * NN * sizeof(float),
                   hipMemcpyDeviceToDevice, stream);
}

// Round 4
// 90.310 us; speedup vs baseline: 1.0937x; 1.0788x over previous
//
#include <hip/hip_runtime.h>
#include <math.h>

// BispectrumCalculator:
//   y = fft(target)  [B,T,N] complex
//   Bx[k,l] = y[k] * conj(y[l]) * y[(l-k) mod N]
//   source = stack([Bx.re, Bx.im], ch).mean(T)  -> [B, 2, N, N]
//   outputs: (source, target)  -> d_out = source flat (16,777,216) ++ target flat (65,536)
//
// r2/r3 post-mortem: measured window includes harness re-poison of d_ws
// (269 MB, ~45us) + d_out (67 MB, ~12us); controllable slice ~35-40us.
// bispec is near its 64 MiB store floor (~11us); dft was 4 waves/CU
// latency-bound -> split n-sum (this round); passthrough fused into dft.

#define NN 512
#define TT 4
#define BB 32

// ---------------------------------------------------------------------------
// Kernel A: DFT-512 per (b,t), n-split for occupancy.
// Grid = 512 blocks x 256 threads. Block = (bt, k-quarter).
//   tid = nh*128 + kl : k = kq*128 + kl, n-range = [nh*256, nh*256+256)
// Each thread: 64 groups of 4 n's with 4 complex rotors (chain length 64).
// Rotor seeds via exact mod-512 phase reduction. nh=1 partials combined
// through LDS. kq==0 threads also copy the target row to the output tail
// (second tuple output) -- removes the separate memcpy dispatch.
// ---------------------------------------------------------------------------
__global__ __launch_bounds__(256) void dft_kernel(const float* __restrict__ x,
                                                  float2* __restrict__ y,
                                                  float* __restrict__ tail) {
    __shared__ float2 part[128];

    int bt = blockIdx.x >> 2;
    int kq = blockIdx.x & 3;
    int kl = threadIdx.x & 127;
    int nh = threadIdx.x >> 7;
    int k  = (kq << 7) | kl;
    const float* xp = x + (size_t)bt * NN;

    // fused passthrough: one quarter-block per bt copies its target row
    if (kq == 0 && nh == 0) {
        ((float4*)(tail + (size_t)bt * NN))[kl] = ((const float4*)xp)[kl];
    }

    int n0 = nh << 8;  // 0 or 256
    const float twopi_n = -2.0f * (float)M_PI / (float)NN;

    // rotor seeds w_j = exp(i*ang*(n0+j)), phases reduced mod 512 exactly
    float2 w0, w1, w2, w3;
    float s4, c4;
    {
        int m0 = (k * (n0 + 0)) & (NN - 1);
        int m1 = (k * (n0 + 1)) & (NN - 1);
        int m2 = (k * (n0 + 2)) & (NN - 1);
        int m3 = (k * (n0 + 3)) & (NN - 1);
        int m4 = (k * 4) & (NN - 1);
        sincosf(twopi_n * (float)m0, &w0.y, &w0.x);
        sincosf(twopi_n * (float)m1, &w1.y, &w1.x);
        sincosf(twopi_n * (float)m2, &w2.y, &w2.x);
        sincosf(twopi_n * (float)m3, &w3.y, &w3.x);
        sincosf(twopi_n * (float)m4, &s4, &c4);
    }

    float2 a0 = make_float2(0.f, 0.f), a1 = a0, a2 = a0, a3 = a0;

    #pragma unroll 4
    for (int n = n0; n < n0 + 256; n += 4) {
        float x0 = xp[n];
        float x1 = xp[n + 1];
        float x2 = xp[n + 2];
        float x3 = xp[n + 3];
        a0.x += x0 * w0.x; a0.y += x0 * w0.y;
        a1.x += x1 * w1.x; a1.y += x1 * w1.y;
        a2.x += x2 * w2.x; a2.y += x2 * w2.y;
        a3.x += x3 * w3.x; a3.y += x3 * w3.y;
        float t;
        t = w0.x * c4 - w0.y * s4; w0.y = w0.x * s4 + w0.y * c4; w0.x = t;
        t = w1.x * c4 - w1.y * s4; w1.y = w1.x * s4 + w1.y * c4; w1.x = t;
        t = w2.x * c4 - w2.y * s4; w2.y = w2.x * s4 + w2.y * c4; w2.x = t;
        t = w3.x * c4 - w3.y * s4; w3.y = w3.x * s4 + w3.y * c4; w3.x = t;
    }

    float re = (a0.x + a1.x) + (a2.x + a3.x);
    float im = (a0.y + a1.y) + (a2.y + a3.y);

    if (nh == 1) {
        part[kl] = make_float2(re, im);
    }
    __syncthreads();
    if (nh == 0) {
        float2 p = part[kl];
        y[(size_t)bt * NN + k] = make_float2(re + p.x, im + p.y);
    }
}

// ---------------------------------------------------------------------------
// Kernel B: bispectrum, register-sliding-window (unchanged from r3).
// Grid = B * 64 blocks of 256 threads; block = one b, 8 consecutive k-rows.
// Doubled LDS ring per t removes the mod-512 wrap -> 8-wide contiguous
// c-windows read once per t, reused across 8 k. Near the 64 MiB store floor.
// ---------------------------------------------------------------------------
__global__ __launch_bounds__(256) void bispec_kernel(const float2* __restrict__ y,
                                                     float* __restrict__ out) {
    __shared__ float2 ring[TT * 2 * NN];  // 32 KiB, doubled ring per t

    int b     = blockIdx.x >> 6;
    int kbase = (blockIdx.x & 63) << 3;
    int tid   = threadIdx.x;

    // stage y[b] -> doubled LDS ring (global: [t][256] float4)
    const float4* src = (const float4*)(y + (size_t)b * TT * NN);
    float4* dst4 = (float4*)ring;
    #pragma unroll
    for (int i = 0; i < 4; ++i) {
        int g = tid + 256 * i;          // [0,1024)
        int t = g >> 8;
        int j = g & 255;
        float4 v = src[g];
        dst4[(t << 9) + j]       = v;
        dst4[(t << 9) + j + 256] = v;
    }
    __syncthreads();

    int l0 = tid;  // second l is l0 + 256

    // conj-source values, k-invariant
    float2 b0[TT], b1[TT];
    #pragma unroll
    for (int t = 0; t < TT; ++t) {
        b0[t] = ring[(t << 10) + l0];
        b1[t] = ring[(t << 10) + l0 + 256];
    }

    float r0[8], i0[8], r1[8], i1[8];
    #pragma unroll
    for (int kk = 0; kk < 8; ++kk) { r0[kk] = i0[kk] = r1[kk] = i1[kk] = 0.f; }

    int w0base = (l0 - kbase - 7) & (NN - 1);        // window start, half 0
    int w1base = (l0 + 256 - kbase - 7) & (NN - 1);  // window start, half 1

    #pragma unroll
    for (int t = 0; t < TT; ++t) {
        const float2* rt = ring + (t << 10);
        float2 cw0[8], cw1[8], av[8];
        #pragma unroll
        for (int j = 0; j < 8; ++j) {
            cw0[j] = rt[w0base + j];
            cw1[j] = rt[w1base + j];
            av[j]  = rt[kbase + j];   // wave-uniform broadcast
        }
        #pragma unroll
        for (int kk = 0; kk < 8; ++kk) {
            float2 a  = av[kk];
            float2 c0 = cw0[7 - kk];
            float2 c1 = cw1[7 - kk];
            float ur0 = a.x * c0.x - a.y * c0.y;
            float ui0 = a.x * c0.y + a.y * c0.x;
            r0[kk] += ur0 * b0[t].x + ui0 * b0[t].y;
            i0[kk] += ui0 * b0[t].x - ur0 * b0[t].y;
            float ur1 = a.x * c1.x - a.y * c1.y;
            float ui1 = a.x * c1.y + a.y * c1.x;
            r1[kk] += ur1 * b1[t].x + ui1 * b1[t].y;
            i1[kk] += ui1 * b1[t].x - ur1 * b1[t].y;
        }
    }

    float* outb = out + (size_t)b * 2 * NN * NN;
    #pragma unroll
    for (int kk = 0; kk < 8; ++kk) {
        size_t rk = (size_t)(kbase + kk) * NN + l0;
        outb[rk]                 = r0[kk] * 0.25f;  // real ch, l0
        outb[rk + 256]           = r1[kk] * 0.25f;  // real ch, l0+256
        outb[NN * NN + rk]       = i0[kk] * 0.25f;  // imag ch, l0
        outb[NN * NN + rk + 256] = i1[kk] * 0.25f;  // imag ch, l0+256
    }
}

extern "C" void kernel_launch(void* const* d_in, const int* in_sizes, int n_in,
                              void* d_out, int out_size, void* d_ws, size_t ws_size,
                              hipStream_t stream) {
    const float* target = (const float*)d_in[0];
    float* out = (float*)d_out;
    // workspace: y spectrum, B*T*N complex64 = 512 KiB
    float2* y = (float2*)d_ws;
    float* tail = out + (size_t)BB * 2 * NN * NN;  // target passthrough

    dft_kernel<<<BB * TT * 4, 256, 0, stream>>>(target, y, tail);
    bispec_kernel<<<BB * 64, 256, 0, stream>>>(y, out);
}